// Round 6
// baseline (319.205 us; speedup 1.0000x reference)
//
#include <hip/hip_runtime.h>
#include <math.h>

// Problem constants (from setup_inputs)
#define T_TOTAL 2097152
#define A_DIM   18
#define GAMMA_D 0.99

#define CHUNK 256
#define NC    (T_TOTAL / CHUNK)        // 8192 chunks
#define KTR   14                       // G^14 ~ 2e-16, G = 0.99^256 ~ 0.076
#define CPB   4                        // chunks per block
#define NB    (NC / CPB)               // 2048 blocks
#define BLK   512                      // 8 waves; 2 rows/thread

// ---------------------------------------------------------------------------
// Single fused kernel. Block b owns chunks [4b,4b+3] = rows [1024b,1024b+1023].
//  phase 0a: issue ALL ep_rs loads first (oldest in vmcnt queue -> phase 1 can
//            wait on them WITHOUT draining the weight stream behind them)
//  phase 0b: issue weight/act loads (consumed in phase 3, stay in flight)
//  phase 1:  window sums L[c0+1..c0+17] (wave-reduce), -> LDS
//  phase 2:  waves 0-3: own-chunk d via lane suffix scan (bit-exact k_d logic)
//  phase 3:  per-thread 2 rows: register logsumexp (exact reference op order),
//            accumulate {sum d, sum nlp, sum nlp*d} in f64
//  epilogue: block reduce -> 3 device atomicAdd(f64); last block (flag) reads
//            coherent totals and writes the final scalar. No second kernel.
__global__ __launch_bounds__(BLK, 4)
void k_mega(const float* __restrict__ wgt, const int* __restrict__ act,
            const float* __restrict__ r, double* __restrict__ acc,
            unsigned int* __restrict__ flag, float* __restrict__ out) {
    __shared__ double ldsL[17];               // window chunk-sums
    __shared__ double ldsD[CPB * CHUNK];      // d for the block's 1024 rows (8 KB)
    __shared__ double red[24];
    const int tid  = threadIdx.x;
    const int lane = tid & 63, wv = tid >> 6;      // wv in 0..7
    const int c0   = blockIdx.x * CPB;
    const double g  = GAMMA_D;
    const double G_ = pow(g, 256.0);
    const double w4 = pow(g, (double)(4 * lane));

    // ---- phase 0a: ep_rs loads (window: k = wv, wv+8, wv+16; own: wv<4) ----
    const int cc0 = c0 + 1 + wv;
    const int cc1 = c0 + 1 + wv + 8;
    const int cc2 = c0 + 1 + wv + 16;
    float4 rv0 = (cc0 < NC) ? ((const float4*)r)[(size_t)cc0 * 64 + lane] : make_float4(0,0,0,0);
    float4 rv1 = (cc1 < NC) ? ((const float4*)r)[(size_t)cc1 * 64 + lane] : make_float4(0,0,0,0);
    float4 rv2 = (wv == 0 && cc2 < NC) ? ((const float4*)r)[(size_t)cc2 * 64 + lane] : make_float4(0,0,0,0);
    float4 rown = (wv < CPB) ? ((const float4*)r)[(size_t)(c0 + wv) * 64 + lane] : make_float4(0,0,0,0);

    // ---- phase 0b: weight/act loads for this thread's 2 rows ----
    const size_t rowBase = (size_t)blockIdx.x * (CPB * CHUNK);
    const float4* wp = (const float4*)(wgt + (rowBase + 2 * (size_t)tid) * A_DIM);
    float4 a[9];
    #pragma unroll
    for (int q = 0; q < 9; ++q) a[q] = wp[q];
    const int2 aa = *(const int2*)(act + rowBase + 2 * tid);

    // ---- phase 1: window chunk sums (independent reduces -> ILP) ----
    double vs0 = w4 * ((double)rv0.x + g * ((double)rv0.y + g * ((double)rv0.z + g * (double)rv0.w)));
    double vs1 = w4 * ((double)rv1.x + g * ((double)rv1.y + g * ((double)rv1.z + g * (double)rv1.w)));
    double vs2 = w4 * ((double)rv2.x + g * ((double)rv2.y + g * ((double)rv2.z + g * (double)rv2.w)));
    #pragma unroll
    for (int off = 32; off > 0; off >>= 1) {
        vs0 += __shfl_down(vs0, off, 64);
        vs1 += __shfl_down(vs1, off, 64);
        vs2 += __shfl_down(vs2, off, 64);
    }
    if (lane == 0) {
        ldsL[wv]     = vs0;                   // k = 0..7
        ldsL[wv + 8] = vs1;                   // k = 8..15
        if (wv == 0) ldsL[16] = vs2;          // k = 16
    }
    __syncthreads();

    // ---- phase 2: own-chunk d (waves 0..3), k_d logic verbatim ----
    if (wv < CPB) {
        double acc_c = 0.0, wG = 1.0;
        #pragma unroll
        for (int m = 0; m < KTR; ++m) { acc_c += wG * ldsL[wv + m]; wG *= G_; }
        const double u3 = (double)rown.w;
        const double u2 = (double)rown.z + g * u3;
        const double u1 = (double)rown.y + g * u2;
        const double u0 = (double)rown.x + g * u1;
        double S = w4 * u0;
        #pragma unroll
        for (int off = 1; off < 64; off <<= 1) {
            const double t = __shfl_down(S, off, 64);
            S += (lane + off < 64) ? t : 0.0;
        }
        double Snext = __shfl_down(S, 1, 64);
        if (lane == 63) Snext = 0.0;
        const double A  = (1.0 / w4) * (Snext + G_ * acc_c);
        const double ig = 1.0 / g;
        double* dp = ldsD + wv * CHUNK + 4 * lane;
        dp[0] = u0 + A;
        dp[1] = u1 + ig * A;
        dp[2] = u2 + (ig * ig) * A;
        dp[3] = u3 + (ig * ig * ig) * A;
    }
    __syncthreads();

    // ---- phase 3: logsumexp on 2 rows (exact reference op order) ----
    const double2 dd = *(const double2*)(ldsD + 2 * tid);
    double s_n = 0.0, s_nd = 0.0;
    double s_d = dd.x + dd.y;
    float w[36];
    #pragma unroll
    for (int q = 0; q < 9; ++q) {
        w[4*q+0] = a[q].x; w[4*q+1] = a[q].y; w[4*q+2] = a[q].z; w[4*q+3] = a[q].w;
    }
    {   // row 0
        float mx = w[0];
        #pragma unroll
        for (int j = 1; j < A_DIM; ++j) mx = fmaxf(mx, w[j]);
        float s = 0.0f, wsel = 0.0f;
        #pragma unroll
        for (int j = 0; j < A_DIM; ++j) { s += expf(w[j] - mx); wsel = (j == aa.x) ? w[j] : wsel; }
        const float nlp = mx + logf(s) - wsel;
        s_n += (double)nlp;  s_nd += (double)nlp * dd.x;
    }
    {   // row 1
        float mx = w[18];
        #pragma unroll
        for (int j = 1; j < A_DIM; ++j) mx = fmaxf(mx, w[18 + j]);
        float s = 0.0f, wsel = 0.0f;
        #pragma unroll
        for (int j = 0; j < A_DIM; ++j) { s += expf(w[18 + j] - mx); wsel = (j == aa.y) ? w[18 + j] : wsel; }
        const float nlp = mx + logf(s) - wsel;
        s_n += (double)nlp;  s_nd += (double)nlp * dd.y;
    }

    // ---- epilogue: block reduce, device atomics, last-block finalize ----
    #pragma unroll
    for (int off = 32; off > 0; off >>= 1) {
        s_d  += __shfl_down(s_d,  off, 64);
        s_n  += __shfl_down(s_n,  off, 64);
        s_nd += __shfl_down(s_nd, off, 64);
    }
    if (lane == 0) { red[wv*3+0] = s_d; red[wv*3+1] = s_n; red[wv*3+2] = s_nd; }
    __syncthreads();
    if (tid == 0) {
        double pa = 0.0, pb = 0.0, pc = 0.0;
        #pragma unroll
        for (int q = 0; q < 8; ++q) { pa += red[q*3]; pb += red[q*3+1]; pc += red[q*3+2]; }
        atomicAdd(&acc[0], pa);
        atomicAdd(&acc[1], pb);
        atomicAdd(&acc[2], pc);
        __threadfence();                       // value-atomics visible before flag
        const unsigned int old = atomicAdd(flag, 1u);
        if (old == NB - 1) {                   // I am the last block
            __threadfence();
            const double sd  = atomicAdd(&acc[0], 0.0);  // coherent RMW read
            const double sn  = atomicAdd(&acc[1], 0.0);
            const double snd = atomicAdd(&acc[2], 0.0);
            const double invT = 1.0 / (double)T_TOTAL;
            // out = (1/T) * ( sum(nlp*d) - mean(d) * sum(nlp) )
            out[0] = (float)((snd - (sd * invT) * sn) * invT);
        }
    }
}

// ---------------------------------------------------------------------------
extern "C" void kernel_launch(void* const* d_in, const int* in_sizes, int n_in,
                              void* d_out, int out_size, void* d_ws, size_t ws_size,
                              hipStream_t stream) {
    const float* weight = (const float*)d_in[0];   // [T, 18] f32
    const float* ep_rs  = (const float*)d_in[1];   // [T] f32
    const int*   ep_as  = (const int*)  d_in[2];   // [T] int
    float* out = (float*)d_out;

    double*       acc  = (double*)d_ws;            // acc[0..2]: sum d / nlp / nlp*d
    unsigned int* flag = (unsigned int*)((char*)d_ws + 24);

    // zero accumulators + completion flag (workspace is poisoned every iter)
    hipMemsetAsync(d_ws, 0, 64, stream);
    k_mega<<<NB, BLK, 0, stream>>>(weight, ep_as, ep_rs, acc, flag, out);
}